// Round 1
// baseline (437.584 us; speedup 1.0000x reference)
//
#include <hip/hip_runtime.h>
#include <math.h>

#define TPB 256
// LDS swizzle at float2 (8B) granularity, bijective on [0,2048). For every
// wave access pattern in this kernel (strides 1,4,32,256 and the digit-
// reversed scatter) each bank-quad is hit exactly 4x per 64-lane b64 access,
// which is the conflict-free minimum (128 words over 32 banks).
#define SWZ(i) ((i) ^ (((i) >> 5) & 31) ^ ((i) >> 10))

// Angle constants
#define A2048 0.0030679615757712823f   // 2*pi/2048
#define A256  0.0245436926061702596f   // 2*pi/256
#define A32   0.1963495408493620774f   // 2*pi/32
#define APACK 0.0015339807878856411f   // pi/2048
#define EPSB  1.220703125e-4f          // 2^-13 selection band

__device__ __forceinline__ float2 cadd(float2 a, float2 b){return make_float2(a.x+b.x, a.y+b.y);}
__device__ __forceinline__ float2 csub(float2 a, float2 b){return make_float2(a.x-b.x, a.y-b.y);}
__device__ __forceinline__ float2 cmul(float2 a, float2 b){return make_float2(a.x*b.x-a.y*b.y, a.x*b.y+a.y*b.x);}
__device__ __forceinline__ float2 cni(float2 a){return make_float2(a.y, -a.x);}   // -i*a
__device__ __forceinline__ float2 cpi(float2 a){return make_float2(-a.y, a.x);}   // +i*a

// After DIF stages with radices [8,8,8,4], frequency k sits at pos2048(k).
__device__ __forceinline__ int pos2048(int k) {
  return 256*(k&7) + 32*((k>>3)&7) + 4*((k>>6)&7) + ((k>>9)&3);
}

__device__ __forceinline__ void fft8(float2 y[8]) {
  const float S2 = 0.70710678118654752f;
  float2 B0=cadd(y[0],y[4]), B4=csub(y[0],y[4]);
  float2 B1=cadd(y[1],y[5]), B5=csub(y[1],y[5]);
  float2 B2=cadd(y[2],y[6]), B6=csub(y[2],y[6]);
  float2 B3=cadd(y[3],y[7]), B7=csub(y[3],y[7]);
  float2 C0=cadd(B0,B2), C2=csub(B0,B2);
  float2 C1=cadd(B1,B3), C3=csub(B1,B3);
  float2 n6=cni(B6), n7=cni(B7);
  float2 C4=cadd(B4,n6), C6=csub(B4,n6);
  float2 C5=cadd(B5,n7), C7=csub(B5,n7);
  y[0]=cadd(C0,C1); y[4]=csub(C0,C1);
  float2 n3=cni(C3);
  y[2]=cadd(C2,n3); y[6]=csub(C2,n3);
  float2 t5=make_float2(S2*(C5.x+C5.y), S2*(C5.y-C5.x));       // w8*C5
  y[1]=cadd(C4,t5); y[5]=csub(C4,t5);
  float2 t7=make_float2(S2*(C7.y-C7.x), -S2*(C7.x+C7.y));      // w8^3*C7
  y[3]=cadd(C6,t7); y[7]=csub(C6,t7);
}

__device__ __forceinline__ void ifft8(float2 y[8]) {
  const float S2 = 0.70710678118654752f;
  float2 B0=cadd(y[0],y[4]), B4=csub(y[0],y[4]);
  float2 B1=cadd(y[1],y[5]), B5=csub(y[1],y[5]);
  float2 B2=cadd(y[2],y[6]), B6=csub(y[2],y[6]);
  float2 B3=cadd(y[3],y[7]), B7=csub(y[3],y[7]);
  float2 C0=cadd(B0,B2), C2=csub(B0,B2);
  float2 C1=cadd(B1,B3), C3=csub(B1,B3);
  float2 p6=cpi(B6), p7=cpi(B7);
  float2 C4=cadd(B4,p6), C6=csub(B4,p6);
  float2 C5=cadd(B5,p7), C7=csub(B5,p7);
  y[0]=cadd(C0,C1); y[4]=csub(C0,C1);
  float2 p3=cpi(C3);
  y[2]=cadd(C2,p3); y[6]=csub(C2,p3);
  float2 t5=make_float2(S2*(C5.x-C5.y), S2*(C5.x+C5.y));       // conj(w8)*C5
  y[1]=cadd(C4,t5); y[5]=csub(C4,t5);
  float2 t7=make_float2(-S2*(C7.x+C7.y), S2*(C7.x-C7.y));      // conj(w8)^3*C7
  y[3]=cadd(C6,t7); y[7]=csub(C6,t7);
}

// One radix-8 stage: DIF fwd = butterfly then twiddle W^(j*s); DIT inv =
// conj-twiddle then inverse butterfly. a1 carries the sign.
__device__ __forceinline__ void r8stage(float2* Zf, int idx0, int st, float a1, bool inv) {
  float2 y[8];
#pragma unroll
  for (int s=0;s<8;++s) y[s]=Zf[SWZ(idx0+st*s)];
  float sn, cs; __sincosf(a1, &sn, &cs);
  float2 w1=make_float2(cs,sn);
  float2 w2=cmul(w1,w1), w3=cmul(w2,w1), w4=cmul(w2,w2);
  float2 w5=cmul(w4,w1), w6=cmul(w4,w2), w7=cmul(w4,w3);
  if (inv){
    y[1]=cmul(y[1],w1); y[2]=cmul(y[2],w2); y[3]=cmul(y[3],w3);
    y[4]=cmul(y[4],w4); y[5]=cmul(y[5],w5); y[6]=cmul(y[6],w6); y[7]=cmul(y[7],w7);
    ifft8(y);
  } else {
    fft8(y);
    y[1]=cmul(y[1],w1); y[2]=cmul(y[2],w2); y[3]=cmul(y[3],w3);
    y[4]=cmul(y[4],w4); y[5]=cmul(y[5],w5); y[6]=cmul(y[6],w6); y[7]=cmul(y[7],w7);
  }
#pragma unroll
  for (int s=0;s<8;++s) Zf[SWZ(idx0+st*s)] = y[s];
}

// (B, R, Cd) -> (B, Cd, R) transpose, 64x64 tiles, float4 on both sides.
// 1-D grid of 8192 blocks; XCD-grouped remap: id%8 picks the XCD (HW
// round-robin), 8 CONSECUTIVE tiles land on the same XCD so their strided
// 256-B output chunks coalesce into ~2KB regions within one L2 before
// write-back (and adjacent read regions share DRAM pages).
// Requires (R/64)*(Cd/64) == 128 tiles per batch (true for both calls).
__global__ __launch_bounds__(256) void tposeX(const float* __restrict__ in,
                                              float* __restrict__ out,
                                              int R, int Cd, int lgx) {
  __shared__ float tile[64][65];
  int t = threadIdx.x;
  int q = t & 15, r = t >> 4;
  int id = blockIdx.x;
  int g = id & 7, j = id >> 3;
  int w = ((j >> 3) << 6) | (g << 3) | (j & 7);   // bijective on [0,8192)
  int b = w >> 7;                                  // 128 tiles per batch
  int rem = w & 127;
  int gxm = (1 << lgx) - 1;
  int c0 = (rem & gxm) * 64, r0 = (rem >> lgx) * 64;
  const float4* in4 = reinterpret_cast<const float4*>(in + (size_t)b * R * Cd);
  float4* out4 = reinterpret_cast<float4*>(out + (size_t)b * R * Cd);
#pragma unroll
  for (int rr = r; rr < 64; rr += 16) {
    float4 v = in4[((size_t)(r0 + rr) * Cd + c0) / 4 + q];
    tile[rr][4 * q + 0] = v.x; tile[rr][4 * q + 1] = v.y;
    tile[rr][4 * q + 2] = v.z; tile[rr][4 * q + 3] = v.w;
  }
  __syncthreads();
#pragma unroll
  for (int cc = r; cc < 64; cc += 16) {
    float4 wv;
    wv.x = tile[4 * q + 0][cc]; wv.y = tile[4 * q + 1][cc];
    wv.z = tile[4 * q + 2][cc]; wv.w = tile[4 * q + 3][cc];
    out4[((size_t)(c0 + cc) * R + r0) / 4 + q] = wv;
  }
}

// One block per (b,c) signal: fp32 packed rfft (radix-8 register-resident) ->
// top-k via fp32 radix-select + band + exact fp64 DFT recheck -> fp32 irfft.
// This revision keeps the 2049 |X[k]|^2 keys in REGISTERS (8/thread + Nyquist
// on tid0): keyF LDS array deleted (28.7->23.5 KB LDS => 6 blocks/CU), and the
// radix-select histogram uses 4 WAVE-PRIVATE copies (264-word stride) so the
// exponent-concentrated hot buckets of Gaussian |X|^2 keys serialize 4x less.
__global__ __launch_bounds__(TPB, 6) void fourier_topk_kernel(
    const float* __restrict__ src, float* __restrict__ dst,
    const int* __restrict__ kptr, int strideT) {
  __shared__ float2 Zf[2048];            // 16 KB
  __shared__ unsigned int histL[1056];   // 4 wave-private hists, stride 264
  __shared__ unsigned char maskA[2052];
  __shared__ int tieIdx[64];
  __shared__ double candV[64];
  __shared__ double cpR[4], cpI[4];
  __shared__ unsigned int bcD, bcR, bcCnt, bcT, bcG, bcTieN;

  const int tid = threadIdx.x;
  int i = blockIdx.x;
  int xj = i & 7, mm = i >> 3;
  int c = 16 * xj + (mm & 15);
  int b = mm >> 4;
  const size_t base = (strideT == 1) ? ((size_t)(b * 128 + c)) * 4096
                                     : ((size_t)b * 4096 * 128 + (size_t)c);
  const float* sp = src + base;
  float* dp = dst + base;

  // ---- load to LDS only (no register copy) ----
  if (strideT == 1) {
    const float4* sp4 = reinterpret_cast<const float4*>(sp);
#pragma unroll
    for (int it = 0; it < 4; ++it) {
      int t4 = tid + 256 * it;
      float4 v = sp4[t4];
      Zf[SWZ(2*t4)]   = make_float2(v.x, v.y);
      Zf[SWZ(2*t4+1)] = make_float2(v.z, v.w);
    }
  } else {
#pragma unroll
    for (int it = 0; it < 8; ++it) {
      int n = tid + 256 * it;
      float a = sp[(size_t)(2*n) * strideT];
      float bb = sp[(size_t)(2*n+1) * strideT];
      Zf[SWZ(n)] = make_float2(a, bb);
    }
  }
  __syncthreads();

  // ---- forward FFT: radices [8,8,8,4], natural -> pos2048 order ----
  r8stage(Zf, tid, 256, -A2048 * (float)tid, false);
  __syncthreads();
  r8stage(Zf, 256*(tid>>5) + (tid&31), 32, -A256 * (float)(tid&31), false);
  __syncthreads();
  r8stage(Zf, 32*(tid>>2) + (tid&3), 4, -A32 * (float)(tid&3), false);
  __syncthreads();
#pragma unroll
  for (int h = 0; h < 2; ++h) {          // final radix-4, no twiddle
    int i0 = 4 * (tid + 256*h);
    float2 A0=Zf[SWZ(i0)], A1=Zf[SWZ(i0+1)], A2=Zf[SWZ(i0+2)], A3=Zf[SWZ(i0+3)];
    float2 f=cadd(A0,A2), e=csub(A0,A2), g=cadd(A1,A3), d=csub(A1,A3);
    float2 nd=cni(d);
    Zf[SWZ(i0)]   = cadd(f,g);
    Zf[SWZ(i0+1)] = cadd(e,nd);
    Zf[SWZ(i0+2)] = csub(f,g);
    Zf[SWZ(i0+3)] = csub(e,nd);
  }
  __syncthreads();

  // ---- keys in REGISTERS, pairwise unpack: thread owns
  //   kA[j] = |X[tid+256j]|^2        (k in [0,1024), tid0/j0 -> k=0)
  //   kB[j] = |X[2048-(tid+256j)]|^2 (k in (1024,2048], tid0/j0 -> k=2048)
  //   kNy   = |X[1024]|^2            (used by tid0 only)
  float kA[4], kB[4];
#pragma unroll
  for (int jj = 0; jj < 4; ++jj) {
    int k = tid + 256 * jj;                       // k in [0,1024)
    float2 za = Zf[SWZ(pos2048(k))];
    float2 zb = Zf[SWZ(pos2048((2048 - k) & 2047))];
    float her = 0.5f*(za.x+zb.x), hei = 0.5f*(za.y-zb.y);
    float hor = 0.5f*(za.y+zb.y), hoi = -0.5f*(za.x-zb.x);
    float sn, cs; __sincosf(-APACK * (float)k, &sn, &cs);
    float whr = cs*hor - sn*hoi, whi = cs*hoi + sn*hor;
    float x1r = her + whr, x1i = hei + whi;       // X[k]
    float x2r = her - whr, x2i = whi - hei;       // X[2048-k]
    kA[jj] = x1r*x1r + x1i*x1i;
    kB[jj] = x2r*x2r + x2i*x2i;
  }
  float kNy;
  {                                               // k = 1024 (self-paired)
    float2 za = Zf[SWZ(pos2048(1024))];           // uniform addr: broadcast
    kNy = za.x*za.x + za.y*za.y;
  }
  const bool hasNy = (tid == 0);

  // ---- radix select (4x8-bit) on fp32 key bits, keys from registers ----
  int kk = kptr[0];
  if (kk > 2049) kk = 2049;
  if (kk < 1) kk = 1;
  unsigned int prefix = 0u, pmask = 0u, Tkey = 0u;
  bool haveT = false;
  int R = kk;
  unsigned int* myh = &histL[(tid >> 6) * 264];   // wave-private copy
#pragma unroll 1
  for (int p = 0; p < 4; ++p) {
    if (!haveT) {
      const int sh = 24 - 8 * p;
      for (int idx2 = tid; idx2 < 1056; idx2 += TPB) histL[idx2] = 0u;
      __syncthreads();
#pragma unroll
      for (int jj = 0; jj < 4; ++jj) {
        unsigned int u = __float_as_uint(kA[jj]);
        if ((u & pmask) == prefix) atomicAdd(&myh[(u >> sh) & 255u], 1u);
        u = __float_as_uint(kB[jj]);
        if ((u & pmask) == prefix) atomicAdd(&myh[(u >> sh) & 255u], 1u);
      }
      if (hasNy) {
        unsigned int u = __float_as_uint(kNy);
        if ((u & pmask) == prefix) atomicAdd(&myh[(u >> sh) & 255u], 1u);
      }
      __syncthreads();
      if (tid < 64) {                     // single-wave suffix scan, 256 buckets
        int L = tid;
        int s0 = 0, s1 = 0, s2 = 0, s3 = 0;
#pragma unroll
        for (int wv = 0; wv < 4; ++wv) {
          const unsigned int* hw = &histL[wv * 264];
          s0 += (int)hw[4*L]; s1 += (int)hw[4*L+1];
          s2 += (int)hw[4*L+2]; s3 += (int)hw[4*L+3];
        }
        int loc = s0 + s1 + s2 + s3;
        int suf = loc;
#pragma unroll
        for (int off = 1; off < 64; off <<= 1) {
          int tt = __shfl(suf, (L + off) & 63, 64);
          suf += (L + off < 64) ? tt : 0;
        }
        int e3 = suf - loc, i3 = e3 + s3;
        int e2 = i3,        i2 = e2 + s2;
        int e1 = i2,        i1 = e1 + s1;
        int e0 = i1,        i0 = e0 + s0;
        if (e3 < R && R <= i3) { bcD = 4*L+3; bcR = R - e3; bcCnt = s3; }
        if (e2 < R && R <= i2) { bcD = 4*L+2; bcR = R - e2; bcCnt = s2; }
        if (e1 < R && R <= i1) { bcD = 4*L+1; bcR = R - e1; bcCnt = s1; }
        if (e0 < R && R <= i0) { bcD = 4*L+0; bcR = R - e0; bcCnt = s0; }
      }
      __syncthreads();
      prefix |= (bcD << sh);
      pmask |= (255u << sh);
      R = (int)bcR;
      if (bcCnt == 1u) {
#pragma unroll
        for (int jj = 0; jj < 4; ++jj) {
          unsigned int u = __float_as_uint(kA[jj]);
          if ((u & pmask) == prefix) bcT = u;
          u = __float_as_uint(kB[jj]);
          if ((u & pmask) == prefix) bcT = u;
        }
        if (hasNy) {
          unsigned int u = __float_as_uint(kNy);
          if ((u & pmask) == prefix) bcT = u;
        }
        __syncthreads();
        Tkey = bcT;
        haveT = true;
      }
      __syncthreads();
    }
  }
  if (!haveT) Tkey = prefix;

  // ---- band around threshold; exact-fp64 recheck only if band is split ----
  float Tf = __uint_as_float(Tkey);
  float Thi = Tf * (1.0f + EPSB), Tlo = Tf * (1.0f - EPSB);
  if (tid == 0) { bcG = 0u; bcTieN = 0u; }
  __syncthreads();
#pragma unroll
  for (int jj = 0; jj < 4; ++jj) {
    float v = kA[jj];
    if (v > Thi) atomicAdd(&bcG, 1u);
    else if (v >= Tlo) {
      int pos = (int)atomicAdd(&bcTieN, 1u);
      if (pos < 64) tieIdx[pos] = tid + 256 * jj;
    }
    v = kB[jj];
    if (v > Thi) atomicAdd(&bcG, 1u);
    else if (v >= Tlo) {
      int pos = (int)atomicAdd(&bcTieN, 1u);
      if (pos < 64) tieIdx[pos] = 2048 - (tid + 256 * jj);
    }
  }
  if (hasNy) {
    if (kNy > Thi) atomicAdd(&bcG, 1u);
    else if (kNy >= Tlo) {
      int pos = (int)atomicAdd(&bcTieN, 1u);
      if (pos < 64) tieIdx[pos] = 1024;
    }
  }
  __syncthreads();
  int G = (int)bcG, E = (int)bcTieN, need = kk - G;

  if (need >= E) {   // common path: every band member kept
#pragma unroll
    for (int jj = 0; jj < 4; ++jj) {
      int k = tid + 256 * jj;
      maskA[k]        = (kA[jj] >= Tlo) ? 1 : 0;
      maskA[2048 - k] = (kB[jj] >= Tlo) ? 1 : 0;
    }
    if (hasNy) maskA[1024] = (kNy >= Tlo) ? 1 : 0;
    __syncthreads();
  } else {           // band split: exact fp64 DFT on candidates (reload input)
#pragma unroll
    for (int jj = 0; jj < 4; ++jj) {
      int k = tid + 256 * jj;
      maskA[k]        = (kA[jj] > Thi) ? 1 : 0;
      maskA[2048 - k] = (kB[jj] > Thi) ? 1 : 0;
    }
    if (hasNy) maskA[1024] = (kNy > Thi) ? 1 : 0;
    __syncthreads();
    int nt = E < 64 ? E : 64;
    for (int ci = 0; ci < nt; ++ci) {
      int kq = tieIdx[ci];
      double sr = 0.0, si = 0.0;
#pragma unroll 1
      for (int j = 0; j < 16; ++j) {
        int m = tid + 256 * j;
        double xm = (double)sp[(size_t)m * strideT];   // src intact (dst written later)
        int a = (kq * m) & 4095;
        double ang = 1.5339807878856412e-3 * (double)a;   // 2*pi/4096 * a
        double sv, cv; sincos(ang, &sv, &cv);
        sr += xm * cv; si -= xm * sv;
      }
#pragma unroll
      for (int off = 1; off < 64; off <<= 1) {
        sr += __shfl_xor(sr, off); si += __shfl_xor(si, off);
      }
      if ((tid & 63) == 0) { cpR[tid >> 6] = sr; cpI[tid >> 6] = si; }
      __syncthreads();
      if (tid == 0) {
        double Rr = cpR[0]+cpR[1]+cpR[2]+cpR[3];
        double Ii = cpI[0]+cpI[1]+cpI[2]+cpI[3];
        candV[ci] = Rr*Rr + Ii*Ii;
      }
      __syncthreads();
    }
    if (tid == 0) {
      unsigned char* ch = (unsigned char*)histL;   // reuse (histL free now)
      for (int t = 0; t < nt; ++t) ch[t] = 0;
      int lim = need < nt ? need : nt;
      for (int s = 0; s < lim; ++s) {
        int best = -1;
        for (int t = 0; t < nt; ++t) {
          if (ch[t]) continue;
          if (best < 0 || candV[t] > candV[best] ||
              (candV[t] == candV[best] && tieIdx[t] < tieIdx[best])) best = t;
        }
        if (best >= 0) { ch[best] = 1; maskA[tieIdx[best]] = 1; }
      }
    }
    __syncthreads();
  }

  // ---- filter + repack, PAIRWISE IN-PLACE (thread-local pairs, no barrier):
  // pair (k, 2048-k) reads exactly {Zf[pos(k)], Zf[pos(2048-k)]} and writes
  // the same two slots. Z'[2048-k] = 0.5(sr+ti, tr-si) from k's intermediates.
#pragma unroll
  for (int jj = 0; jj < 4; ++jj) {
    int k = tid + 256 * jj;
    if (k == 0) {                                 // k=0 and k=1024 specials
      int p0 = SWZ(pos2048(0));
      float2 z0 = Zf[p0];
      float X0 = z0.x + z0.y, XN = z0.x - z0.y;
      float A = maskA[0] ? X0 : 0.0f, Bv = maskA[2048] ? XN : 0.0f;
      Zf[p0] = make_float2(0.5f*(A + Bv), 0.5f*(A - Bv));
      int p1 = SWZ(pos2048(1024));
      float2 z1 = Zf[p1];
      float m1 = maskA[1024] ? 1.0f : 0.0f;
      Zf[p1] = make_float2(m1 * z1.x, m1 * z1.y);
    } else {                                      // k in [1,1024)
      int pa = SWZ(pos2048(k)), pb = SWZ(pos2048(2048 - k));
      float2 za = Zf[pa], zb = Zf[pb];
      float her = 0.5f*(za.x+zb.x), hei = 0.5f*(za.y-zb.y);
      float hor = 0.5f*(za.y+zb.y), hoi = -0.5f*(za.x-zb.x);
      float sn, cs; __sincosf(-APACK * (float)k, &sn, &cs);
      float wr = cs, wi = sn;
      float whr = wr*hor - wi*hoi, whi = wr*hoi + wi*hor;
      float x1r = her + whr, x1i = hei + whi;     // X[k]
      float x2r = her - whr, x2i = whi - hei;     // X[2048-k]
      float mA = maskA[k] ? 1.0f : 0.0f, mB = maskA[2048 - k] ? 1.0f : 0.0f;
      float Ar = mA*x1r, Ai = mA*x1i, Br = mB*x2r, Bi = mB*x2i;
      float sr = Ar + Br, si = Ai - Bi;
      float dr = Ar - Br, di = Ai + Bi;
      float tr = wr*dr + wi*di, ti = wr*di - wi*dr;   // conj(W)*d
      Zf[pa] = make_float2(0.5f*(sr - ti), 0.5f*(si + tr));
      Zf[pb] = make_float2(0.5f*(sr + ti), 0.5f*(tr - si));
    }
  }
  __syncthreads();

  // ---- inverse FFT: radices [4,8,8,8], pos2048 -> natural order ----
#pragma unroll
  for (int h = 0; h < 2; ++h) {          // inverse radix-4
    int i0 = 4 * (tid + 256*h);
    float2 y0=Zf[SWZ(i0)], y1=Zf[SWZ(i0+1)], y2=Zf[SWZ(i0+2)], y3=Zf[SWZ(i0+3)];
    float2 f=cadd(y0,y2), e=csub(y0,y2), g=cadd(y1,y3), d=csub(y1,y3);
    float2 pd=cpi(d);
    Zf[SWZ(i0)]   = cadd(f,g);
    Zf[SWZ(i0+1)] = cadd(e,pd);
    Zf[SWZ(i0+2)] = csub(f,g);
    Zf[SWZ(i0+3)] = csub(e,pd);
  }
  __syncthreads();
  r8stage(Zf, 32*(tid>>2) + (tid&3), 4, A32 * (float)(tid&3), true);
  __syncthreads();
  r8stage(Zf, 256*(tid>>5) + (tid&31), 32, A256 * (float)(tid&31), true);
  __syncthreads();
  r8stage(Zf, tid, 256, A2048 * (float)tid, true);
  __syncthreads();

  // ---- store (scale 1/2048 for the unnormalized fwd/inv pair) ----
  const float scf = 1.0f / 2048.0f;
  if (strideT == 1) {
    float4* dp4 = reinterpret_cast<float4*>(dp);
#pragma unroll
    for (int it = 0; it < 4; ++it) {
      int t4 = tid + 256 * it;
      float2 v0 = Zf[SWZ(2*t4)], v1 = Zf[SWZ(2*t4+1)];
      dp4[t4] = make_float4(v0.x*scf, v0.y*scf, v1.x*scf, v1.y*scf);
    }
  } else {
#pragma unroll
    for (int it = 0; it < 8; ++it) {
      int n = tid + 256 * it;
      float2 v = Zf[SWZ(n)];
      dp[(size_t)(2*n) * strideT]   = v.x * scf;
      dp[(size_t)(2*n+1) * strideT] = v.y * scf;
    }
  }
}

extern "C" void kernel_launch(void* const* d_in, const int* in_sizes, int n_in,
                              void* d_out, int out_size, void* d_ws, size_t ws_size,
                              hipStream_t stream) {
  (void)in_sizes; (void)n_in; (void)out_size;
  const float* ts = (const float*)d_in[0];
  const int* kptr = (const int*)d_in[1];
  float* out = (float*)d_out;
  float* ws = (float*)d_ws;
  const int B = 64, S = 4096, C = 128;
  const size_t sigBytes = (size_t)B * S * C * sizeof(float);

  if (ws_size >= sigBytes) {
    // (B,S,C) -> (B,C,S) -> per-signal FFT/top-k in-place -> (B,S,C)
    // tposeX grids: 8192 blocks = B * (R/64) * (Cd/64); lgx = log2(Cd/64).
    tposeX<<<8192, 256, 0, stream>>>(ts, ws, S, C, 1);
    fourier_topk_kernel<<<B * C, TPB, 0, stream>>>(ws, ws, kptr, 1);
    tposeX<<<8192, 256, 0, stream>>>(ws, out, C, S, 6);
  } else {
    // Fallback: direct strided access (XCD-swizzled block->signal mapping).
    fourier_topk_kernel<<<B * C, TPB, 0, stream>>>(ts, out, kptr, C);
  }
}

// Round 2
// 417.890 us; speedup vs baseline: 1.0471x; 1.0471x over previous
//
#include <hip/hip_runtime.h>
#include <math.h>

#define TPB 256
// LDS swizzle at float2 (8B) granularity, bijective on [0,2048). For every
// wave access pattern in this kernel (strides 1,4,32,256 and the digit-
// reversed scatter) each bank-quad is hit exactly 4x per 64-lane b64 access,
// which is the conflict-free minimum (128 words over 32 banks).
// NOTE (R1 post-mortem): SQ_LDS_BANK_CONFLICT ~2.45e7 is the structural b64
// floor of these FFT passes (identical across kernel revisions) - not a lever.
#define SWZ(i) ((i) ^ (((i) >> 5) & 31) ^ ((i) >> 10))

// Angle constants
#define A2048 0.0030679615757712823f   // 2*pi/2048
#define A256  0.0245436926061702596f   // 2*pi/256
#define A32   0.1963495408493620774f   // 2*pi/32
#define APACK 0.0015339807878856411f   // pi/2048
#define EPSB  1.220703125e-4f          // 2^-13 selection band

__device__ __forceinline__ float2 cadd(float2 a, float2 b){return make_float2(a.x+b.x, a.y+b.y);}
__device__ __forceinline__ float2 csub(float2 a, float2 b){return make_float2(a.x-b.x, a.y-b.y);}
__device__ __forceinline__ float2 cmul(float2 a, float2 b){return make_float2(a.x*b.x-a.y*b.y, a.x*b.y+a.y*b.x);}
__device__ __forceinline__ float2 cni(float2 a){return make_float2(a.y, -a.x);}   // -i*a
__device__ __forceinline__ float2 cpi(float2 a){return make_float2(-a.y, a.x);}   // +i*a

// After DIF stages with radices [8,8,8,4], frequency k sits at pos2048(k).
__device__ __forceinline__ int pos2048(int k) {
  return 256*(k&7) + 32*((k>>3)&7) + 4*((k>>6)&7) + ((k>>9)&3);
}

__device__ __forceinline__ void fft8(float2 y[8]) {
  const float S2 = 0.70710678118654752f;
  float2 B0=cadd(y[0],y[4]), B4=csub(y[0],y[4]);
  float2 B1=cadd(y[1],y[5]), B5=csub(y[1],y[5]);
  float2 B2=cadd(y[2],y[6]), B6=csub(y[2],y[6]);
  float2 B3=cadd(y[3],y[7]), B7=csub(y[3],y[7]);
  float2 C0=cadd(B0,B2), C2=csub(B0,B2);
  float2 C1=cadd(B1,B3), C3=csub(B1,B3);
  float2 n6=cni(B6), n7=cni(B7);
  float2 C4=cadd(B4,n6), C6=csub(B4,n6);
  float2 C5=cadd(B5,n7), C7=csub(B5,n7);
  y[0]=cadd(C0,C1); y[4]=csub(C0,C1);
  float2 n3=cni(C3);
  y[2]=cadd(C2,n3); y[6]=csub(C2,n3);
  float2 t5=make_float2(S2*(C5.x+C5.y), S2*(C5.y-C5.x));       // w8*C5
  y[1]=cadd(C4,t5); y[5]=csub(C4,t5);
  float2 t7=make_float2(S2*(C7.y-C7.x), -S2*(C7.x+C7.y));      // w8^3*C7
  y[3]=cadd(C6,t7); y[7]=csub(C6,t7);
}

__device__ __forceinline__ void ifft8(float2 y[8]) {
  const float S2 = 0.70710678118654752f;
  float2 B0=cadd(y[0],y[4]), B4=csub(y[0],y[4]);
  float2 B1=cadd(y[1],y[5]), B5=csub(y[1],y[5]);
  float2 B2=cadd(y[2],y[6]), B6=csub(y[2],y[6]);
  float2 B3=cadd(y[3],y[7]), B7=csub(y[3],y[7]);
  float2 C0=cadd(B0,B2), C2=csub(B0,B2);
  float2 C1=cadd(B1,B3), C3=csub(B1,B3);
  float2 p6=cpi(B6), p7=cpi(B7);
  float2 C4=cadd(B4,p6), C6=csub(B4,p6);
  float2 C5=cadd(B5,p7), C7=csub(B5,p7);
  y[0]=cadd(C0,C1); y[4]=csub(C0,C1);
  float2 p3=cpi(C3);
  y[2]=cadd(C2,p3); y[6]=csub(C2,p3);
  float2 t5=make_float2(S2*(C5.x-C5.y), S2*(C5.x+C5.y));       // conj(w8)*C5
  y[1]=cadd(C4,t5); y[5]=csub(C4,t5);
  float2 t7=make_float2(-S2*(C7.x+C7.y), S2*(C7.x-C7.y));      // conj(w8)^3*C7
  y[3]=cadd(C6,t7); y[7]=csub(C6,t7);
}

// One radix-8 stage: DIF fwd = butterfly then twiddle W^(j*s); DIT inv =
// conj-twiddle then inverse butterfly. a1 carries the sign.
__device__ __forceinline__ void r8stage(float2* Zf, int idx0, int st, float a1, bool inv) {
  float2 y[8];
#pragma unroll
  for (int s=0;s<8;++s) y[s]=Zf[SWZ(idx0+st*s)];
  float sn, cs; __sincosf(a1, &sn, &cs);
  float2 w1=make_float2(cs,sn);
  float2 w2=cmul(w1,w1), w3=cmul(w2,w1), w4=cmul(w2,w2);
  float2 w5=cmul(w4,w1), w6=cmul(w4,w2), w7=cmul(w4,w3);
  if (inv){
    y[1]=cmul(y[1],w1); y[2]=cmul(y[2],w2); y[3]=cmul(y[3],w3);
    y[4]=cmul(y[4],w4); y[5]=cmul(y[5],w5); y[6]=cmul(y[6],w6); y[7]=cmul(y[7],w7);
    ifft8(y);
  } else {
    fft8(y);
    y[1]=cmul(y[1],w1); y[2]=cmul(y[2],w2); y[3]=cmul(y[3],w3);
    y[4]=cmul(y[4],w4); y[5]=cmul(y[5],w5); y[6]=cmul(y[6],w6); y[7]=cmul(y[7],w7);
  }
#pragma unroll
  for (int s=0;s<8;++s) Zf[SWZ(idx0+st*s)] = y[s];
}

// Transpose call 1: in (B, R=4096, C=128) -> out (B, C, R).
// Tile 128 rows x 64 cols, LDS 128x65 (33 KB, 4 blocks/CU). Writes are
// 512 B-contiguous per C-row (vs 256 B in the 64x64 version); all LDS
// access patterns are 2-way max (free on CDNA4).
__global__ __launch_bounds__(256) void tposeA(const float* __restrict__ in,
                                              float* __restrict__ out) {
  __shared__ float tile[128][65];
  const int R = 4096, C = 128;
  int t = threadIdx.x;
  int b = blockIdx.z;
  int r0 = blockIdx.y * 128;        // 32 r-tiles
  int c0 = blockIdx.x * 64;         // 2 c-tiles
  const float4* in4 = reinterpret_cast<const float4*>(in + (size_t)b * R * C);
  float4* out4 = reinterpret_cast<float4*>(out + (size_t)b * R * C);
  int q = t & 15, r = t >> 4;
#pragma unroll
  for (int it = 0; it < 8; ++it) {
    int rr = r + 16 * it;                               // 0..127
    float4 v = in4[((size_t)(r0 + rr) * C + c0) / 4 + q];
    tile[rr][4*q+0] = v.x; tile[rr][4*q+1] = v.y;
    tile[rr][4*q+2] = v.z; tile[rr][4*q+3] = v.w;
  }
  __syncthreads();
  // out rows = c (64 rows of 4096); each row gets 128 floats (32 float4)
#pragma unroll
  for (int it = 0; it < 8; ++it) {
    int jj = it & 1;                                    // sF half
    int ci = it >> 1;                                   // cc quarter
    int sF = q + 16 * jj;                               // 0..31
    int cc = r + 16 * ci;                               // 0..63
    float4 w;
    w.x = tile[4*sF+0][cc]; w.y = tile[4*sF+1][cc];
    w.z = tile[4*sF+2][cc]; w.w = tile[4*sF+3][cc];
    out4[((size_t)(c0 + cc) * R + r0) / 4 + sF] = w;
  }
}

// Transpose call 2: in (B, R2=128, Cd=4096) -> out (B, Cd, R2).
// Tile 64 c-rows x 128 s-cols, LDS 64x129 (33 KB, 4 blocks/CU). Reads are
// 512 B-contiguous per c-row (vs 256 B at 16 KB stride before).
__global__ __launch_bounds__(256) void tposeB(const float* __restrict__ in,
                                              float* __restrict__ out) {
  __shared__ float tile2[64][129];
  const int R2 = 128, Cd = 4096;
  int t = threadIdx.x;
  int b = blockIdx.z;
  int s0 = blockIdx.x * 128;        // 32 s-tiles
  int r0 = blockIdx.y * 64;         // 2 c-tiles
  const float4* in4 = reinterpret_cast<const float4*>(in + (size_t)b * R2 * Cd);
  float4* out4 = reinterpret_cast<float4*>(out + (size_t)b * R2 * Cd);
  {
    int q = t & 31, w = t >> 5;     // q: s-float4 (32 => 128 s), w: row base
#pragma unroll
    for (int it = 0; it < 8; ++it) {
      int rr = w + 8 * it;                              // 0..63
      float4 v = in4[((size_t)(r0 + rr) * Cd + s0) / 4 + q];
      tile2[rr][4*q+0] = v.x; tile2[rr][4*q+1] = v.y;
      tile2[rr][4*q+2] = v.z; tile2[rr][4*q+3] = v.w;
    }
  }
  __syncthreads();
  // out rows = s (128 rows of 128 floats); block writes 64 c's per row
  {
    int q = t & 15, rh = t >> 4;
#pragma unroll
    for (int it = 0; it < 8; ++it) {
      int ss = rh + 16 * it;                            // 0..127
      float4 w;
      w.x = tile2[4*q+0][ss]; w.y = tile2[4*q+1][ss];
      w.z = tile2[4*q+2][ss]; w.w = tile2[4*q+3][ss];
      out4[((size_t)(s0 + ss) * R2 + r0) / 4 + q] = w;
    }
  }
}

// One block per (b,c) signal: fp32 packed rfft (radix-8 register-resident) ->
// top-k via fp32 radix-select + band + exact fp64 DFT recheck -> fp32 irfft.
// Keys live in REGISTERS (8/thread + Nyquist on tid0). R1 lesson: the (TPB,6)
// VGPR cap spilled the keys to scratch (+490 MB HBM traffic) - bound is back
// to the proven (TPB,4). maskA is aliased onto histL (dead after select) and
// the tie-path scratch onto cpRI, LDS 23.5 -> 21.5 KB (7 blocks/CU if VGPR<=72).
__global__ __launch_bounds__(TPB, 4) void fourier_topk_kernel(
    const float* __restrict__ src, float* __restrict__ dst,
    const int* __restrict__ kptr, int strideT) {
  __shared__ float2 Zf[2048];            // 16 KB
  __shared__ unsigned int histL[1056];   // 4 wave-private hists, stride 264
  __shared__ int tieIdx[64];
  __shared__ double candV[64];
  __shared__ double cpRI[8];             // partial sums; tie-path ch scratch later
  __shared__ unsigned int bcD, bcR, bcCnt, bcT, bcG, bcTieN;
  // maskA aliases histL: histL is dead once the radix select finishes, and
  // every maskA use (writes in band/tie phases, reads in repack) is after it.
  unsigned char* maskA = reinterpret_cast<unsigned char*>(histL);   // [0..2048]

  const int tid = threadIdx.x;
  int i = blockIdx.x;
  int xj = i & 7, mm = i >> 3;
  int c = 16 * xj + (mm & 15);
  int b = mm >> 4;
  const size_t base = (strideT == 1) ? ((size_t)(b * 128 + c)) * 4096
                                     : ((size_t)b * 4096 * 128 + (size_t)c);
  const float* sp = src + base;
  float* dp = dst + base;

  // ---- load to LDS only (no register copy) ----
  if (strideT == 1) {
    const float4* sp4 = reinterpret_cast<const float4*>(sp);
#pragma unroll
    for (int it = 0; it < 4; ++it) {
      int t4 = tid + 256 * it;
      float4 v = sp4[t4];
      Zf[SWZ(2*t4)]   = make_float2(v.x, v.y);
      Zf[SWZ(2*t4+1)] = make_float2(v.z, v.w);
    }
  } else {
#pragma unroll
    for (int it = 0; it < 8; ++it) {
      int n = tid + 256 * it;
      float a = sp[(size_t)(2*n) * strideT];
      float bb = sp[(size_t)(2*n+1) * strideT];
      Zf[SWZ(n)] = make_float2(a, bb);
    }
  }
  __syncthreads();

  // ---- forward FFT: radices [8,8,8,4], natural -> pos2048 order ----
  r8stage(Zf, tid, 256, -A2048 * (float)tid, false);
  __syncthreads();
  r8stage(Zf, 256*(tid>>5) + (tid&31), 32, -A256 * (float)(tid&31), false);
  __syncthreads();
  r8stage(Zf, 32*(tid>>2) + (tid&3), 4, -A32 * (float)(tid&3), false);
  __syncthreads();
#pragma unroll
  for (int h = 0; h < 2; ++h) {          // final radix-4, no twiddle
    int i0 = 4 * (tid + 256*h);
    float2 A0=Zf[SWZ(i0)], A1=Zf[SWZ(i0+1)], A2=Zf[SWZ(i0+2)], A3=Zf[SWZ(i0+3)];
    float2 f=cadd(A0,A2), e=csub(A0,A2), g=cadd(A1,A3), d=csub(A1,A3);
    float2 nd=cni(d);
    Zf[SWZ(i0)]   = cadd(f,g);
    Zf[SWZ(i0+1)] = cadd(e,nd);
    Zf[SWZ(i0+2)] = csub(f,g);
    Zf[SWZ(i0+3)] = csub(e,nd);
  }
  __syncthreads();

  // ---- keys in REGISTERS, pairwise unpack: thread owns
  //   kA[j] = |X[tid+256j]|^2        (k in [0,1024), tid0/j0 -> k=0)
  //   kB[j] = |X[2048-(tid+256j)]|^2 (k in (1024,2048], tid0/j0 -> k=2048)
  //   kNy   = |X[1024]|^2            (used by tid0 only)
  float kA[4], kB[4];
#pragma unroll
  for (int jj = 0; jj < 4; ++jj) {
    int k = tid + 256 * jj;                       // k in [0,1024)
    float2 za = Zf[SWZ(pos2048(k))];
    float2 zb = Zf[SWZ(pos2048((2048 - k) & 2047))];
    float her = 0.5f*(za.x+zb.x), hei = 0.5f*(za.y-zb.y);
    float hor = 0.5f*(za.y+zb.y), hoi = -0.5f*(za.x-zb.x);
    float sn, cs; __sincosf(-APACK * (float)k, &sn, &cs);
    float whr = cs*hor - sn*hoi, whi = cs*hoi + sn*hor;
    float x1r = her + whr, x1i = hei + whi;       // X[k]
    float x2r = her - whr, x2i = whi - hei;       // X[2048-k]
    kA[jj] = x1r*x1r + x1i*x1i;
    kB[jj] = x2r*x2r + x2i*x2i;
  }
  float kNy;
  {                                               // k = 1024 (self-paired)
    float2 za = Zf[SWZ(pos2048(1024))];           // uniform addr: broadcast
    kNy = za.x*za.x + za.y*za.y;
  }
  const bool hasNy = (tid == 0);

  // ---- radix select (4x8-bit) on fp32 key bits, keys from registers ----
  int kk = kptr[0];
  if (kk > 2049) kk = 2049;
  if (kk < 1) kk = 1;
  unsigned int prefix = 0u, pmask = 0u, Tkey = 0u;
  bool haveT = false;
  int R = kk;
  unsigned int* myh = &histL[(tid >> 6) * 264];   // wave-private copy
#pragma unroll 1
  for (int p = 0; p < 4; ++p) {
    if (!haveT) {
      const int sh = 24 - 8 * p;
      for (int idx2 = tid; idx2 < 1056; idx2 += TPB) histL[idx2] = 0u;
      __syncthreads();
#pragma unroll
      for (int jj = 0; jj < 4; ++jj) {
        unsigned int u = __float_as_uint(kA[jj]);
        if ((u & pmask) == prefix) atomicAdd(&myh[(u >> sh) & 255u], 1u);
        u = __float_as_uint(kB[jj]);
        if ((u & pmask) == prefix) atomicAdd(&myh[(u >> sh) & 255u], 1u);
      }
      if (hasNy) {
        unsigned int u = __float_as_uint(kNy);
        if ((u & pmask) == prefix) atomicAdd(&myh[(u >> sh) & 255u], 1u);
      }
      __syncthreads();
      if (tid < 64) {                     // single-wave suffix scan, 256 buckets
        int L = tid;
        int s0 = 0, s1 = 0, s2 = 0, s3 = 0;
#pragma unroll
        for (int wv = 0; wv < 4; ++wv) {
          const unsigned int* hw = &histL[wv * 264];
          s0 += (int)hw[4*L]; s1 += (int)hw[4*L+1];
          s2 += (int)hw[4*L+2]; s3 += (int)hw[4*L+3];
        }
        int loc = s0 + s1 + s2 + s3;
        int suf = loc;
#pragma unroll
        for (int off = 1; off < 64; off <<= 1) {
          int tt = __shfl(suf, (L + off) & 63, 64);
          suf += (L + off < 64) ? tt : 0;
        }
        int e3 = suf - loc, i3 = e3 + s3;
        int e2 = i3,        i2 = e2 + s2;
        int e1 = i2,        i1 = e1 + s1;
        int e0 = i1,        i0 = e0 + s0;
        if (e3 < R && R <= i3) { bcD = 4*L+3; bcR = R - e3; bcCnt = s3; }
        if (e2 < R && R <= i2) { bcD = 4*L+2; bcR = R - e2; bcCnt = s2; }
        if (e1 < R && R <= i1) { bcD = 4*L+1; bcR = R - e1; bcCnt = s1; }
        if (e0 < R && R <= i0) { bcD = 4*L+0; bcR = R - e0; bcCnt = s0; }
      }
      __syncthreads();
      prefix |= (bcD << sh);
      pmask |= (255u << sh);
      R = (int)bcR;
      if (bcCnt == 1u) {
#pragma unroll
        for (int jj = 0; jj < 4; ++jj) {
          unsigned int u = __float_as_uint(kA[jj]);
          if ((u & pmask) == prefix) bcT = u;
          u = __float_as_uint(kB[jj]);
          if ((u & pmask) == prefix) bcT = u;
        }
        if (hasNy) {
          unsigned int u = __float_as_uint(kNy);
          if ((u & pmask) == prefix) bcT = u;
        }
        __syncthreads();
        Tkey = bcT;
        haveT = true;
      }
      __syncthreads();
    }
  }
  if (!haveT) Tkey = prefix;

  // ---- band around threshold; exact-fp64 recheck only if band is split ----
  float Tf = __uint_as_float(Tkey);
  float Thi = Tf * (1.0f + EPSB), Tlo = Tf * (1.0f - EPSB);
  if (tid == 0) { bcG = 0u; bcTieN = 0u; }
  __syncthreads();
#pragma unroll
  for (int jj = 0; jj < 4; ++jj) {
    float v = kA[jj];
    if (v > Thi) atomicAdd(&bcG, 1u);
    else if (v >= Tlo) {
      int pos = (int)atomicAdd(&bcTieN, 1u);
      if (pos < 64) tieIdx[pos] = tid + 256 * jj;
    }
    v = kB[jj];
    if (v > Thi) atomicAdd(&bcG, 1u);
    else if (v >= Tlo) {
      int pos = (int)atomicAdd(&bcTieN, 1u);
      if (pos < 64) tieIdx[pos] = 2048 - (tid + 256 * jj);
    }
  }
  if (hasNy) {
    if (kNy > Thi) atomicAdd(&bcG, 1u);
    else if (kNy >= Tlo) {
      int pos = (int)atomicAdd(&bcTieN, 1u);
      if (pos < 64) tieIdx[pos] = 1024;
    }
  }
  __syncthreads();
  int G = (int)bcG, E = (int)bcTieN, need = kk - G;

  if (need >= E) {   // common path: every band member kept
#pragma unroll
    for (int jj = 0; jj < 4; ++jj) {
      int k = tid + 256 * jj;
      maskA[k]        = (kA[jj] >= Tlo) ? 1 : 0;
      maskA[2048 - k] = (kB[jj] >= Tlo) ? 1 : 0;
    }
    if (hasNy) maskA[1024] = (kNy >= Tlo) ? 1 : 0;
    __syncthreads();
  } else {           // band split: exact fp64 DFT on candidates (reload input)
#pragma unroll
    for (int jj = 0; jj < 4; ++jj) {
      int k = tid + 256 * jj;
      maskA[k]        = (kA[jj] > Thi) ? 1 : 0;
      maskA[2048 - k] = (kB[jj] > Thi) ? 1 : 0;
    }
    if (hasNy) maskA[1024] = (kNy > Thi) ? 1 : 0;
    __syncthreads();
    int nt = E < 64 ? E : 64;
    for (int ci = 0; ci < nt; ++ci) {
      int kq = tieIdx[ci];
      double sr = 0.0, si = 0.0;
#pragma unroll 1
      for (int j = 0; j < 16; ++j) {
        int m = tid + 256 * j;
        double xm = (double)sp[(size_t)m * strideT];   // src intact (dst written later)
        int a = (kq * m) & 4095;
        double ang = 1.5339807878856412e-3 * (double)a;   // 2*pi/4096 * a
        double sv, cv; sincos(ang, &sv, &cv);
        sr += xm * cv; si -= xm * sv;
      }
#pragma unroll
      for (int off = 1; off < 64; off <<= 1) {
        sr += __shfl_xor(sr, off); si += __shfl_xor(si, off);
      }
      if ((tid & 63) == 0) { cpRI[tid >> 6] = sr; cpRI[4 + (tid >> 6)] = si; }
      __syncthreads();
      if (tid == 0) {
        double Rr = cpRI[0]+cpRI[1]+cpRI[2]+cpRI[3];
        double Ii = cpRI[4]+cpRI[5]+cpRI[6]+cpRI[7];
        candV[ci] = Rr*Rr + Ii*Ii;
      }
      __syncthreads();
    }
    if (tid == 0) {
      // ch scratch lives in cpRI (64 B, dead after the candidate loop).
      // NOT in histL: that memory now backs maskA.
      unsigned char* ch = reinterpret_cast<unsigned char*>(cpRI);
      for (int t = 0; t < nt; ++t) ch[t] = 0;
      int lim = need < nt ? need : nt;
      for (int s = 0; s < lim; ++s) {
        int best = -1;
        for (int t = 0; t < nt; ++t) {
          if (ch[t]) continue;
          if (best < 0 || candV[t] > candV[best] ||
              (candV[t] == candV[best] && tieIdx[t] < tieIdx[best])) best = t;
        }
        if (best >= 0) { ch[best] = 1; maskA[tieIdx[best]] = 1; }
      }
    }
    __syncthreads();
  }

  // ---- filter + repack, PAIRWISE IN-PLACE (thread-local pairs, no barrier):
  // pair (k, 2048-k) reads exactly {Zf[pos(k)], Zf[pos(2048-k)]} and writes
  // the same two slots. Z'[2048-k] = 0.5(sr+ti, tr-si) from k's intermediates.
#pragma unroll
  for (int jj = 0; jj < 4; ++jj) {
    int k = tid + 256 * jj;
    if (k == 0) {                                 // k=0 and k=1024 specials
      int p0 = SWZ(pos2048(0));
      float2 z0 = Zf[p0];
      float X0 = z0.x + z0.y, XN = z0.x - z0.y;
      float A = maskA[0] ? X0 : 0.0f, Bv = maskA[2048] ? XN : 0.0f;
      Zf[p0] = make_float2(0.5f*(A + Bv), 0.5f*(A - Bv));
      int p1 = SWZ(pos2048(1024));
      float2 z1 = Zf[p1];
      float m1 = maskA[1024] ? 1.0f : 0.0f;
      Zf[p1] = make_float2(m1 * z1.x, m1 * z1.y);
    } else {                                      // k in [1,1024)
      int pa = SWZ(pos2048(k)), pb = SWZ(pos2048(2048 - k));
      float2 za = Zf[pa], zb = Zf[pb];
      float her = 0.5f*(za.x+zb.x), hei = 0.5f*(za.y-zb.y);
      float hor = 0.5f*(za.y+zb.y), hoi = -0.5f*(za.x-zb.x);
      float sn, cs; __sincosf(-APACK * (float)k, &sn, &cs);
      float wr = cs, wi = sn;
      float whr = wr*hor - wi*hoi, whi = wr*hoi + wi*hor;
      float x1r = her + whr, x1i = hei + whi;     // X[k]
      float x2r = her - whr, x2i = whi - hei;     // X[2048-k]
      float mA = maskA[k] ? 1.0f : 0.0f, mB = maskA[2048 - k] ? 1.0f : 0.0f;
      float Ar = mA*x1r, Ai = mA*x1i, Br = mB*x2r, Bi = mB*x2i;
      float sr = Ar + Br, si = Ai - Bi;
      float dr = Ar - Br, di = Ai + Bi;
      float tr = wr*dr + wi*di, ti = wr*di - wi*dr;   // conj(W)*d
      Zf[pa] = make_float2(0.5f*(sr - ti), 0.5f*(si + tr));
      Zf[pb] = make_float2(0.5f*(sr + ti), 0.5f*(tr - si));
    }
  }
  __syncthreads();

  // ---- inverse FFT: radices [4,8,8,8], pos2048 -> natural order ----
#pragma unroll
  for (int h = 0; h < 2; ++h) {          // inverse radix-4
    int i0 = 4 * (tid + 256*h);
    float2 y0=Zf[SWZ(i0)], y1=Zf[SWZ(i0+1)], y2=Zf[SWZ(i0+2)], y3=Zf[SWZ(i0+3)];
    float2 f=cadd(y0,y2), e=csub(y0,y2), g=cadd(y1,y3), d=csub(y1,y3);
    float2 pd=cpi(d);
    Zf[SWZ(i0)]   = cadd(f,g);
    Zf[SWZ(i0+1)] = cadd(e,pd);
    Zf[SWZ(i0+2)] = csub(f,g);
    Zf[SWZ(i0+3)] = csub(e,pd);
  }
  __syncthreads();
  r8stage(Zf, 32*(tid>>2) + (tid&3), 4, A32 * (float)(tid&3), true);
  __syncthreads();
  r8stage(Zf, 256*(tid>>5) + (tid&31), 32, A256 * (float)(tid&31), true);
  __syncthreads();
  r8stage(Zf, tid, 256, A2048 * (float)tid, true);
  __syncthreads();

  // ---- store (scale 1/2048 for the unnormalized fwd/inv pair) ----
  const float scf = 1.0f / 2048.0f;
  if (strideT == 1) {
    float4* dp4 = reinterpret_cast<float4*>(dp);
#pragma unroll
    for (int it = 0; it < 4; ++it) {
      int t4 = tid + 256 * it;
      float2 v0 = Zf[SWZ(2*t4)], v1 = Zf[SWZ(2*t4+1)];
      dp4[t4] = make_float4(v0.x*scf, v0.y*scf, v1.x*scf, v1.y*scf);
    }
  } else {
#pragma unroll
    for (int it = 0; it < 8; ++it) {
      int n = tid + 256 * it;
      float2 v = Zf[SWZ(n)];
      dp[(size_t)(2*n) * strideT]   = v.x * scf;
      dp[(size_t)(2*n+1) * strideT] = v.y * scf;
    }
  }
}

extern "C" void kernel_launch(void* const* d_in, const int* in_sizes, int n_in,
                              void* d_out, int out_size, void* d_ws, size_t ws_size,
                              hipStream_t stream) {
  (void)in_sizes; (void)n_in; (void)out_size;
  const float* ts = (const float*)d_in[0];
  const int* kptr = (const int*)d_in[1];
  float* out = (float*)d_out;
  float* ws = (float*)d_ws;
  const int B = 64, S = 4096, C = 128;
  const size_t sigBytes = (size_t)B * S * C * sizeof(float);

  if (ws_size >= sigBytes) {
    // (B,S,C) -> (B,C,S) -> per-signal FFT/top-k in-place -> (B,S,C)
    tposeA<<<dim3(C / 64, S / 128, B), 256, 0, stream>>>(ts, ws);
    fourier_topk_kernel<<<B * C, TPB, 0, stream>>>(ws, ws, kptr, 1);
    tposeB<<<dim3(S / 128, C / 64, B), 256, 0, stream>>>(ws, out);
  } else {
    // Fallback: direct strided access (XCD-swizzled block->signal mapping).
    fourier_topk_kernel<<<B * C, TPB, 0, stream>>>(ts, out, kptr, C);
  }
}